// Round 1
// baseline (172.480 us; speedup 1.0000x reference)
//
#include <hip/hip_runtime.h>
#include <cstdint>
#include <cstddef>

// DotProductAttention: O = softmax_q(QK^T/8 + log(mask)) @ V
// Rewritten as P = mask * exp(QK^T/8); L[b,k] = sum_q P; O = P @ (diag(1/L) V).
// No max-subtraction needed: S <= ~6 for N(0,1) inputs -> exp fits fp32 easily.

#define LSEQ 2048
#define DHEAD 64
#define NB 16

typedef __bf16 v8bf __attribute__((ext_vector_type(8)));
typedef __bf16 v4bf __attribute__((ext_vector_type(4)));
typedef float v4f __attribute__((ext_vector_type(4)));

#define MFMA16(a, b, c) __builtin_amdgcn_mfma_f32_16x16x32_bf16(a, b, c, 0, 0, 0)

__device__ __forceinline__ void gl_lds16(const void* g, void* l) {
  __builtin_amdgcn_global_load_lds(
      (__attribute__((address_space(1))) void*)g,
      (__attribute__((address_space(3))) void*)l, 16, 0, 0);
}

// ---- K0: cast Q,K fp32 -> bf16 ----------------------------------------------
__global__ __launch_bounds__(256) void cast_qk(const float* __restrict__ Q,
                                               const float* __restrict__ K,
                                               __bf16* __restrict__ Qb,
                                               __bf16* __restrict__ Kb) {
  size_t i = ((size_t)blockIdx.x * 256 + threadIdx.x) * 4;
  float4 q = *(const float4*)(Q + i);
  float4 k = *(const float4*)(K + i);
  v4bf qo = {(__bf16)q.x, (__bf16)q.y, (__bf16)q.z, (__bf16)q.w};
  v4bf ko = {(__bf16)k.x, (__bf16)k.y, (__bf16)k.z, (__bf16)k.w};
  *(v4bf*)(Qb + i) = qo;
  *(v4bf*)(Kb + i) = ko;
}

// ---- K1: column stats L[b,k] = sum_q mask*exp(S) ----------------------------
// WG owns (b, 64-wide k' tile), sweeps all q. No atomics, no zero-init.
__global__ __launch_bounds__(256) void stats_k(const __bf16* __restrict__ Qb,
                                               const __bf16* __restrict__ Kb,
                                               const float* __restrict__ mask,
                                               float* __restrict__ Lsum) {
  const int b = blockIdx.x >> 5;
  const int k0 = (blockIdx.x & 31) * 64;
  const int tid = threadIdx.x;
  const int wave = tid >> 6, lane = tid & 63;
  const int quad = lane >> 4, n = lane & 15;

  __shared__ __align__(16) __bf16 Qt[64 * 64];
  __shared__ float psum[4][64];

  // Persistent K fragments: B[k=d][n=k'] = K[k'][d], lane n holds row k0+sub*16+n
  v8bf bk[4][2];
#pragma unroll
  for (int sub = 0; sub < 4; ++sub)
#pragma unroll
    for (int dh = 0; dh < 2; ++dh)
      bk[sub][dh] = *(const v8bf*)(Kb + ((size_t)b * LSEQ + k0 + sub * 16 + n) * DHEAD +
                                   dh * 32 + quad * 8);

  float colsum[4] = {0.f, 0.f, 0.f, 0.f};

  for (int q0 = 0; q0 < LSEQ; q0 += 64) {
    __syncthreads();
    // stage 64x64 bf16 Q tile, XOR-swizzled 16B chunks (conflict-free frag reads)
#pragma unroll
    for (int i = 0; i < 2; ++i) {
      int s = (wave * 2 + i) * 64 + lane;
      int row = s >> 3, gc = (s & 7) ^ (row & 7);
      gl_lds16(Qb + ((size_t)b * LSEQ + q0 + row) * DHEAD + gc * 8, &Qt[s * 8]);
    }
    __syncthreads();

    // A fragments: lane holds Q row (wave*16+n), d = quad*8..+8 per half
    v8bf aq[2];
    const int qr = wave * 16 + n;
#pragma unroll
    for (int dh = 0; dh < 2; ++dh)
      aq[dh] = *(const v8bf*)&Qt[qr * 64 + ((dh * 4 + quad) ^ (qr & 7)) * 8];

#pragma unroll
    for (int sub = 0; sub < 4; ++sub) {
      v4f c = {0.f, 0.f, 0.f, 0.f};
      c = MFMA16(aq[0], bk[sub][0], c);
      c = MFMA16(aq[1], bk[sub][1], c);
      const int kg = k0 + sub * 16 + n;
#pragma unroll
      for (int r = 0; r < 4; ++r) {
        int qg = q0 + wave * 16 + quad * 4 + r;  // C layout: row=quad*4+r, col=n
        float p = mask[(size_t)qg * LSEQ + kg] * __expf(c[r] * 0.125f);
        colsum[sub] += p;
      }
    }
  }

  // reduce over quads (rows) then waves
#pragma unroll
  for (int sub = 0; sub < 4; ++sub) {
    float v = colsum[sub];
    v += __shfl_xor(v, 16);
    v += __shfl_xor(v, 32);
    if (quad == 0) psum[wave][sub * 16 + n] = v;
  }
  __syncthreads();
  if (tid < 64) {
    float s = psum[0][tid] + psum[1][tid] + psum[2][tid] + psum[3][tid];
    Lsum[(size_t)b * LSEQ + k0 + tid] = s;
  }
}

// ---- K2: Vts[b][v][k] = bf16(V[b][k][v] / L[b][k]) --------------------------
__global__ __launch_bounds__(256) void vtrans_k(const float* __restrict__ V,
                                                const float* __restrict__ Lsum,
                                                __bf16* __restrict__ Vts) {
  const int b = blockIdx.x >> 5;
  const int k0 = (blockIdx.x & 31) * 64;
  const int tid = threadIdx.x;
  __shared__ float tile[64][65];
  __shared__ float invl[64];
  if (tid < 64) invl[tid] = 1.0f / Lsum[(size_t)b * LSEQ + k0 + tid];
#pragma unroll
  for (int t = 0; t < 16; ++t) {
    int flat = t * 256 + tid;
    int k = flat >> 6, v = flat & 63;
    tile[k][v] = V[((size_t)b * LSEQ + k0 + k) * DHEAD + v];
  }
  __syncthreads();
#pragma unroll
  for (int t = 0; t < 16; ++t) {
    int flat = t * 256 + tid;
    int v = flat >> 6, k = flat & 63;
    Vts[((size_t)b * DHEAD + v) * LSEQ + k0 + k] = (__bf16)(tile[k][v] * invl[k]);
  }
}

// ---- K3: O = P @ Vts, P recomputed tile-by-tile -----------------------------
// WG owns (b, 64-q tile); grid decode puts all 16 b's of a q-tile on one XCD
// (bx%8 == qt%8) so the fp32 mask slice stays L2-resident.
__global__ __launch_bounds__(256) void attn_k(const __bf16* __restrict__ Qb,
                                              const __bf16* __restrict__ Kb,
                                              const __bf16* __restrict__ Vts,
                                              const float* __restrict__ mask,
                                              float* __restrict__ out) {
  const int b = blockIdx.x >> 5;
  const int q0 = (blockIdx.x & 31) * 64;
  const int tid = threadIdx.x;
  const int wave = tid >> 6, lane = tid & 63;
  const int quad = lane >> 4, n = lane & 15;

  __shared__ __align__(16) __bf16 Kt[64 * 64];
  __shared__ __align__(16) __bf16 Vt[64 * 64];
  __shared__ __align__(16) __bf16 Pt[64 * 72];  // +8 bf16 row pad: conflict-free

  // Q fragments held in registers the whole kernel
  v8bf aq[2];
  {
    const int qr = q0 + wave * 16 + n;
#pragma unroll
    for (int dh = 0; dh < 2; ++dh)
      aq[dh] = *(const v8bf*)(Qb + ((size_t)b * LSEQ + qr) * DHEAD + dh * 32 + quad * 8);
  }

  v4f acc[4];
#pragma unroll
  for (int vs = 0; vs < 4; ++vs) acc[vs] = (v4f){0.f, 0.f, 0.f, 0.f};

  for (int k0 = 0; k0 < LSEQ; k0 += 64) {
    __syncthreads();
    // stage K tile (rows k', chunks d) and V^T tile (rows v, chunks k'), swizzled
#pragma unroll
    for (int i = 0; i < 2; ++i) {
      int s = (wave * 2 + i) * 64 + lane;
      int row = s >> 3, gc = (s & 7) ^ (row & 7);
      gl_lds16(Kb + ((size_t)b * LSEQ + k0 + row) * DHEAD + gc * 8, &Kt[s * 8]);
      gl_lds16(Vts + ((size_t)b * DHEAD + row) * LSEQ + k0 + gc * 8, &Vt[s * 8]);
    }
    __syncthreads();

    // S tile + P = mask*exp(S/8), written to Pt (same-wave rows only)
#pragma unroll
    for (int sub = 0; sub < 4; ++sub) {
      v4f c = {0.f, 0.f, 0.f, 0.f};
      const int kr = sub * 16 + n;
#pragma unroll
      for (int dh = 0; dh < 2; ++dh) {
        v8bf bkf = *(const v8bf*)&Kt[kr * 64 + ((dh * 4 + quad) ^ (kr & 7)) * 8];
        c = MFMA16(aq[dh], bkf, c);
      }
      const int kg = k0 + kr;
#pragma unroll
      for (int r = 0; r < 4; ++r) {
        int qg = q0 + wave * 16 + quad * 4 + r;
        float p = mask[(size_t)qg * LSEQ + kg] * __expf(c[r] * 0.125f);
        Pt[(wave * 16 + quad * 4 + r) * 72 + kr] = (__bf16)p;
      }
    }
    __asm__ volatile("s_waitcnt lgkmcnt(0)" ::: "memory");  // P visible to own wave

    // O += P @ Vt  (A = P rows of own wave; B[k'][v] = Vt[v][k'])
#pragma unroll
    for (int kk = 0; kk < 2; ++kk) {
      v8bf ap = *(const v8bf*)&Pt[(wave * 16 + n) * 72 + kk * 32 + quad * 8];
#pragma unroll
      for (int vs = 0; vs < 4; ++vs) {
        const int vr = vs * 16 + n;
        v8bf bv = *(const v8bf*)&Vt[vr * 64 + ((kk * 4 + quad) ^ (vr & 7)) * 8];
        acc[vs] = MFMA16(ap, bv, acc[vs]);
      }
    }
  }

#pragma unroll
  for (int vs = 0; vs < 4; ++vs)
#pragma unroll
    for (int r = 0; r < 4; ++r)
      out[((size_t)b * LSEQ + q0 + wave * 16 + quad * 4 + r) * DHEAD + vs * 16 + n] =
          acc[vs][r];
}

extern "C" void kernel_launch(void* const* d_in, const int* in_sizes, int n_in,
                              void* d_out, int out_size, void* d_ws, size_t ws_size,
                              hipStream_t stream) {
  const float* Q = (const float*)d_in[0];
  const float* K = (const float*)d_in[1];
  const float* V = (const float*)d_in[2];
  const float* mask = (const float*)d_in[3];
  float* out = (float*)d_out;

  char* ws = (char*)d_ws;
  // ws layout: Qb 4 MiB | Kb 4 MiB | Vts 4 MiB | L 128 KiB  (total 12.2 MiB)
  __bf16* Qb = (__bf16*)(ws);
  __bf16* Kb = (__bf16*)(ws + 4194304);
  __bf16* Vts = (__bf16*)(ws + 8388608);
  float* Lsum = (float*)(ws + 12582912);
  if (ws_size < 12713984) return;  // workspace too small — fail loudly (poison out)

  cast_qk<<<2048, 256, 0, stream>>>(Q, K, Qb, Kb);
  stats_k<<<512, 256, 0, stream>>>(Qb, Kb, mask, Lsum);
  vtrans_k<<<512, 256, 0, stream>>>(V, Lsum, Vts);
  attn_k<<<512, 256, 0, stream>>>(Qb, Kb, Vts, mask, out);
}

// Round 2
// 170.361 us; speedup vs baseline: 1.0124x; 1.0124x over previous
//
#include <hip/hip_runtime.h>
#include <cstdint>
#include <cstddef>

// DotProductAttention: O = softmax_q(QK^T/8 + log(mask)) @ V
// Rewritten as P = mask * exp(QK^T/8); L[b,k] = sum_q P; O = P @ (diag(1/L) V).
// No max-subtraction needed: S <= ~6 for N(0,1) inputs -> exp fits fp32 easily.
// R2: occupancy fix — split reduction axes (q in stats, k in attn), accumulate
// via global_atomic_add_f32 (unsafeAtomicAdd). Grids 512 -> 2048.

#define LSEQ 2048
#define DHEAD 64

typedef __bf16 v8bf __attribute__((ext_vector_type(8)));
typedef __bf16 v4bf __attribute__((ext_vector_type(4)));
typedef float v4f __attribute__((ext_vector_type(4)));

#define MFMA16(a, b, c) __builtin_amdgcn_mfma_f32_16x16x32_bf16(a, b, c, 0, 0, 0)

__device__ __forceinline__ void gl_lds16(const void* g, void* l) {
  __builtin_amdgcn_global_load_lds(
      (__attribute__((address_space(1))) void*)g,
      (__attribute__((address_space(3))) void*)l, 16, 0, 0);
}

// ---- K0: cast Q,K fp32 -> bf16 ----------------------------------------------
__global__ __launch_bounds__(256) void cast_qk(const float* __restrict__ Q,
                                               const float* __restrict__ K,
                                               __bf16* __restrict__ Qb,
                                               __bf16* __restrict__ Kb) {
  size_t i = ((size_t)blockIdx.x * 256 + threadIdx.x) * 4;
  float4 q = *(const float4*)(Q + i);
  float4 k = *(const float4*)(K + i);
  v4bf qo = {(__bf16)q.x, (__bf16)q.y, (__bf16)q.z, (__bf16)q.w};
  v4bf ko = {(__bf16)k.x, (__bf16)k.y, (__bf16)k.z, (__bf16)k.w};
  *(v4bf*)(Qb + i) = qo;
  *(v4bf*)(Kb + i) = ko;
}

// ---- K1: column stats L[b,k] = sum_q mask*exp(S) ----------------------------
// Grid: b(16) x qchunk(4) x ktile(32) = 2048 WGs -> 8 WGs/CU.
// bx = b*128 + qc*32 + kt  => XCD = kt%8: each XCD's mask col-slice = 2 MB (L2).
__global__ __launch_bounds__(256) void stats_k(const __bf16* __restrict__ Qb,
                                               const __bf16* __restrict__ Kb,
                                               const float* __restrict__ mask,
                                               float* __restrict__ Lsum) {
  const int bx = blockIdx.x;
  const int b = bx >> 7;
  const int qc = (bx >> 5) & 3;
  const int k0 = (bx & 31) * 64;
  const int tid = threadIdx.x;
  const int wave = tid >> 6, lane = tid & 63;
  const int quad = lane >> 4, n = lane & 15;

  __shared__ __align__(16) __bf16 Qt[64 * 64];
  __shared__ float psum[4][64];

  // Persistent K fragments: B[k=d][n=k'] = K[k'][d], lane n holds row k0+sub*16+n
  v8bf bk[4][2];
#pragma unroll
  for (int sub = 0; sub < 4; ++sub)
#pragma unroll
    for (int dh = 0; dh < 2; ++dh)
      bk[sub][dh] = *(const v8bf*)(Kb + ((size_t)b * LSEQ + k0 + sub * 16 + n) * DHEAD +
                                   dh * 32 + quad * 8);

  float colsum[4] = {0.f, 0.f, 0.f, 0.f};

  const int qbeg = qc * 512;
  for (int q0 = qbeg; q0 < qbeg + 512; q0 += 64) {
    __syncthreads();
    // stage 64x64 bf16 Q tile, XOR-swizzled 16B chunks (conflict-free frag reads)
#pragma unroll
    for (int i = 0; i < 2; ++i) {
      int s = (wave * 2 + i) * 64 + lane;
      int row = s >> 3, gc = (s & 7) ^ (row & 7);
      gl_lds16(Qb + ((size_t)b * LSEQ + q0 + row) * DHEAD + gc * 8, &Qt[s * 8]);
    }
    __syncthreads();

    // A fragments: lane holds Q row (wave*16+n), d = quad*8..+8 per half
    v8bf aq[2];
    const int qr = wave * 16 + n;
#pragma unroll
    for (int dh = 0; dh < 2; ++dh)
      aq[dh] = *(const v8bf*)&Qt[qr * 64 + ((dh * 4 + quad) ^ (qr & 7)) * 8];

#pragma unroll
    for (int sub = 0; sub < 4; ++sub) {
      v4f c = {0.f, 0.f, 0.f, 0.f};
      c = MFMA16(aq[0], bk[sub][0], c);
      c = MFMA16(aq[1], bk[sub][1], c);
      const int kg = k0 + sub * 16 + n;
#pragma unroll
      for (int r = 0; r < 4; ++r) {
        int qg = q0 + wave * 16 + quad * 4 + r;  // C layout: row=quad*4+r, col=n
        float p = mask[(size_t)qg * LSEQ + kg] * __expf(c[r] * 0.125f);
        colsum[sub] += p;
      }
    }
  }

  // reduce over quads (rows) then waves, one atomic burst per WG
#pragma unroll
  for (int sub = 0; sub < 4; ++sub) {
    float v = colsum[sub];
    v += __shfl_xor(v, 16);
    v += __shfl_xor(v, 32);
    if (quad == 0) psum[wave][sub * 16 + n] = v;
  }
  __syncthreads();
  if (tid < 64) {
    float s = psum[0][tid] + psum[1][tid] + psum[2][tid] + psum[3][tid];
    unsafeAtomicAdd(&Lsum[(size_t)b * LSEQ + k0 + tid], s);
  }
}

// ---- K2: Vts[b][v][k] = bf16(V[b][k][v] / L[b][k]) --------------------------
// Grid: b(16) x ktile32(64) = 1024 WGs -> 4 WGs/CU.
__global__ __launch_bounds__(256) void vtrans_k(const float* __restrict__ V,
                                                const float* __restrict__ Lsum,
                                                __bf16* __restrict__ Vts) {
  const int b = blockIdx.x >> 6;
  const int k0 = (blockIdx.x & 63) * 32;
  const int tid = threadIdx.x;
  __shared__ float tile[32][65];
  __shared__ float invl[32];
  if (tid < 32) invl[tid] = 1.0f / Lsum[(size_t)b * LSEQ + k0 + tid];
#pragma unroll
  for (int t = 0; t < 8; ++t) {
    int flat = t * 256 + tid;
    int k = flat >> 6, v = flat & 63;
    tile[k][v] = V[((size_t)b * LSEQ + k0 + k) * DHEAD + v];
  }
  __syncthreads();
#pragma unroll
  for (int t = 0; t < 8; ++t) {
    int flat = t * 256 + tid;
    int v = flat >> 5, k = flat & 31;
    Vts[((size_t)b * DHEAD + v) * LSEQ + k0 + k] = (__bf16)(tile[k][v] * invl[k]);
  }
}

// ---- K3: O += P_chunk @ Vts, P recomputed tile-by-tile ----------------------
// Grid: b(16) x kchunk(4) x qtile(32) = 2048 WGs; LDS 25.6KB -> 6 WGs/CU.
// bx = b*128 + kc*32 + qt => XCD = qt%8: mask row-slice 2 MB per XCD (L2).
__global__ __launch_bounds__(256) void attn_k(const __bf16* __restrict__ Qb,
                                              const __bf16* __restrict__ Kb,
                                              const __bf16* __restrict__ Vts,
                                              const float* __restrict__ mask,
                                              float* __restrict__ out) {
  const int bx = blockIdx.x;
  const int b = bx >> 7;
  const int kc = (bx >> 5) & 3;
  const int q0 = (bx & 31) * 64;
  const int tid = threadIdx.x;
  const int wave = tid >> 6, lane = tid & 63;
  const int quad = lane >> 4, n = lane & 15;

  __shared__ __align__(16) __bf16 Kt[64 * 64];
  __shared__ __align__(16) __bf16 Vt[64 * 64];
  __shared__ __align__(16) __bf16 Pt[64 * 72];  // +8 bf16 row pad: conflict-free

  // Q fragments held in registers the whole kernel
  v8bf aq[2];
  {
    const int qr = q0 + wave * 16 + n;
#pragma unroll
    for (int dh = 0; dh < 2; ++dh)
      aq[dh] = *(const v8bf*)(Qb + ((size_t)b * LSEQ + qr) * DHEAD + dh * 32 + quad * 8);
  }

  v4f acc[4];
#pragma unroll
  for (int vs = 0; vs < 4; ++vs) acc[vs] = (v4f){0.f, 0.f, 0.f, 0.f};

  const int kbeg = kc * 512;
  for (int k0 = kbeg; k0 < kbeg + 512; k0 += 64) {
    __syncthreads();
    // stage K tile (rows k', chunks d) and V^T tile (rows v, chunks k'), swizzled
#pragma unroll
    for (int i = 0; i < 2; ++i) {
      int s = (wave * 2 + i) * 64 + lane;
      int row = s >> 3, gc = (s & 7) ^ (row & 7);
      gl_lds16(Kb + ((size_t)b * LSEQ + k0 + row) * DHEAD + gc * 8, &Kt[s * 8]);
      gl_lds16(Vts + ((size_t)b * DHEAD + row) * LSEQ + k0 + gc * 8, &Vt[s * 8]);
    }
    __syncthreads();

    // S tile + P = mask*exp(S/8), written to Pt (same-wave rows only)
#pragma unroll
    for (int sub = 0; sub < 4; ++sub) {
      v4f c = {0.f, 0.f, 0.f, 0.f};
      const int kr = sub * 16 + n;
#pragma unroll
      for (int dh = 0; dh < 2; ++dh) {
        v8bf bkf = *(const v8bf*)&Kt[kr * 64 + ((dh * 4 + quad) ^ (kr & 7)) * 8];
        c = MFMA16(aq[dh], bkf, c);
      }
      const int kg = k0 + kr;
#pragma unroll
      for (int r = 0; r < 4; ++r) {
        int qg = q0 + wave * 16 + quad * 4 + r;
        float p = mask[(size_t)qg * LSEQ + kg] * __expf(c[r] * 0.125f);
        Pt[(wave * 16 + quad * 4 + r) * 72 + kr] = (__bf16)p;
      }
    }
    __asm__ volatile("s_waitcnt lgkmcnt(0)" ::: "memory");  // P visible to own wave

    // O += P @ Vt  (A = P rows of own wave; B[k'][v] = Vt[v][k'])
#pragma unroll
    for (int kk = 0; kk < 2; ++kk) {
      v8bf ap = *(const v8bf*)&Pt[(wave * 16 + n) * 72 + kk * 32 + quad * 8];
#pragma unroll
      for (int vs = 0; vs < 4; ++vs) {
        const int vr = vs * 16 + n;
        v8bf bv = *(const v8bf*)&Vt[vr * 64 + ((kk * 4 + quad) ^ (vr & 7)) * 8];
        acc[vs] = MFMA16(ap, bv, acc[vs]);
      }
    }
  }

  // accumulate the k-chunk partial into out (zeroed by memset before launch)
#pragma unroll
  for (int vs = 0; vs < 4; ++vs)
#pragma unroll
    for (int r = 0; r < 4; ++r)
      unsafeAtomicAdd(
          &out[((size_t)b * LSEQ + q0 + wave * 16 + quad * 4 + r) * DHEAD + vs * 16 + n],
          acc[vs][r]);
}

extern "C" void kernel_launch(void* const* d_in, const int* in_sizes, int n_in,
                              void* d_out, int out_size, void* d_ws, size_t ws_size,
                              hipStream_t stream) {
  const float* Q = (const float*)d_in[0];
  const float* K = (const float*)d_in[1];
  const float* V = (const float*)d_in[2];
  const float* mask = (const float*)d_in[3];
  float* out = (float*)d_out;

  char* ws = (char*)d_ws;
  // ws layout: Qb 4 MiB | Kb 4 MiB | Vts 4 MiB | L 128 KiB  (total 12.2 MiB)
  __bf16* Qb = (__bf16*)(ws);
  __bf16* Kb = (__bf16*)(ws + 4194304);
  __bf16* Vts = (__bf16*)(ws + 8388608);
  float* Lsum = (float*)(ws + 12582912);
  if (ws_size < 12713984) return;  // workspace too small — fail loudly (poison out)

  hipMemsetAsync(Lsum, 0, LSEQ * 16 * sizeof(float), stream);
  hipMemsetAsync(out, 0, (size_t)out_size * sizeof(float), stream);
  cast_qk<<<2048, 256, 0, stream>>>(Q, K, Qb, Kb);
  stats_k<<<2048, 256, 0, stream>>>(Qb, Kb, mask, Lsum);
  vtrans_k<<<1024, 256, 0, stream>>>(V, Lsum, Vts);
  attn_k<<<2048, 256, 0, stream>>>(Qb, Kb, Vts, mask, out);
}